// Round 10
// baseline (202.015 us; speedup 1.0000x reference)
//
#include <hip/hip_runtime.h>

#define EMBED 128
#define NEDGES 320000
#define NNODES 10000
#define NUSERS 100000
#define PBLK3 1563    // ceil(100000/64)
#define QBLK3 157     // ceil(10000/64)

typedef __attribute__((ext_vector_type(4))) float f32x4;
typedef __attribute__((ext_vector_type(8))) short bf16x8;
typedef __attribute__((ext_vector_type(4))) short bf16x4;

__device__ __forceinline__ short f2bf(float f) {
  union { float f; unsigned u; } v; v.f = f;
  unsigned r = v.u + 0x7fffu + ((v.u >> 16) & 1u);
  return (short)(r >> 16);
}
// Truncating f32->bf16 (1 op vs 3); softmax shift-invariance cancels the bias.
__device__ __forceinline__ short f2bf_trunc(float f) {
  union { float f; unsigned u; } v; v.f = f;
  return (short)(v.u >> 16);
}
__device__ __forceinline__ float bf2f(short s) {
  union { unsigned u; float f; } v;
  v.u = ((unsigned)(unsigned short)s) << 16;
  return v.f;
}

// ---------------------------------------------------------------------------
// Prep: seg offsets + W1/W2 -> bf16 B-fragment layout.
// ---------------------------------------------------------------------------
__global__ __launch_bounds__(256) void prep_kernel(
    const int* __restrict__ seg_ids, const float* __restrict__ w1,
    const float* __restrict__ w2, int* __restrict__ off,
    short* __restrict__ w1a, short* __restrict__ w1b, short* __restrict__ w2bf) {
  int tid = blockIdx.x * 256 + threadIdx.x;
  if (tid < NEDGES) {
    int cur = seg_ids[tid];
    int prev = (tid == 0) ? -1 : seg_ids[tid - 1];
    for (int n = prev + 1; n <= cur; ++n) off[n] = tid;
    if (tid == NEDGES - 1)
      for (int n = cur + 1; n <= NNODES; ++n) off[n] = NEDGES;
  }
  if (tid < 128 * 256) {
    int n = tid >> 8, k = tid & 255;
    int kk = k & 127;
    int ks = kk >> 5, g = (kk >> 2) & 3, h = (kk >> 4) & 1, j = kk & 3;
    short* dst = (k < 128) ? w1a : w1b;
    dst[(((ks * 4 + g) * 128 + n) << 3) + (h << 2) + j] = f2bf(w1[tid]);
  }
  if (tid < 128 * 128) {
    int n = tid >> 7, kk = tid & 127;
    int ks = kk >> 5, g = (kk >> 2) & 3, h = (kk >> 4) & 1, j = kk & 3;
    w2bf[(((ks * 4 + g) * 128 + n) << 3) + (h << 2) + j] = f2bf(w2[tid]);
  }
}

// ---------------------------------------------------------------------------
// Row-GEMM v4: P path writes the interleaved PU table:
//   PU row u (256 shorts) = [ P fragments (128) | bf16 e_u linear (128) ].
// Q path unchanged (Q_sw, stride 128).  Weights in 32KB LDS; store staging
// overlaid after barrier.
// ---------------------------------------------------------------------------
__global__ __launch_bounds__(256) void row_gemm4_kernel(
    const float* __restrict__ u2e, const int* __restrict__ nodes,
    const short* __restrict__ w1a, const short* __restrict__ w1b,
    const float* __restrict__ b1,
    short* __restrict__ PU, short* __restrict__ Q_sw) {
  __shared__ short lds[16384];  // 32 KB weights; reused as store stage later

  const int tid = threadIdx.x;
  const int lane = tid & 63, wv = tid >> 6;
  const int g = lane >> 4, lm = lane & 15;

  const bool isQ = blockIdx.x >= PBLK3;
  const int blk = isQ ? (int)blockIdx.x - PBLK3 : (int)blockIdx.x;
  const int nrows = isQ ? NNODES : NUSERS;
  const short* wbf = isQ ? w1b : w1a;

#pragma unroll
  for (int i = 0; i < 8; ++i) {
    int o = (i * 256 + tid) << 3;
    *(bf16x8*)&lds[o] = *(const bf16x8*)&wbf[o];
  }
  __syncthreads();

  const int rb = blk * 64 + wv * 16;
  int row = rb + lm;
  int rc = row < nrows ? row : nrows - 1;
  const float* src = u2e + (size_t)(isQ ? nodes[rc] : rc) * EMBED;
  bf16x8 af[4];
#pragma unroll
  for (int ks = 0; ks < 4; ++ks) {
    const float* p = src + 32 * ks + 4 * g;
    f32x4 lo = *(const f32x4*)p;
    f32x4 hi = *(const f32x4*)(p + 16);
    bf16x8 a;
    a[0] = f2bf(lo.x); a[1] = f2bf(lo.y); a[2] = f2bf(lo.z); a[3] = f2bf(lo.w);
    a[4] = f2bf(hi.x); a[5] = f2bf(hi.y); a[6] = f2bf(hi.z); a[7] = f2bf(hi.w);
    af[ks] = a;
    if (!isQ) {  // bf16 e_u copy into the second half of the PU row
      short* dst = PU + (size_t)rc * 256 + 128 + 32 * ks + 4 * g;
      *(bf16x4*)dst = (bf16x4){a[0], a[1], a[2], a[3]};
      *(bf16x4*)(dst + 16) = (bf16x4){a[4], a[5], a[6], a[7]};
    }
  }

  f32x4 acc[8];
#pragma unroll
  for (int nt = 0; nt < 8; ++nt) acc[nt] = (f32x4){0.f, 0.f, 0.f, 0.f};

#pragma unroll
  for (int ks = 0; ks < 4; ++ks) {
#pragma unroll
    for (int nt = 0; nt < 8; ++nt) {
      bf16x8 b = *(const bf16x8*)&lds[((((ks * 4 + g) * 128) + nt * 16 + lm) << 3)];
      acc[nt] = __builtin_amdgcn_mfma_f32_16x16x32_bf16(af[ks], b, acc[nt], 0, 0, 0);
    }
  }
  __syncthreads();  // weights no longer needed; LDS reusable

  short* st = &lds[wv * 2176];  // 16 rows x 136 shorts
#pragma unroll
  for (int nt = 0; nt < 8; ++nt) {
    float bs = isQ ? b1[nt * 16 + lm] : 0.f;
    int fragoff = (((nt >> 1) * 4 + (lm >> 2)) << 3) + ((nt & 1) << 2) + (lm & 3);
#pragma unroll
    for (int r = 0; r < 4; ++r)
      st[(4 * g + r) * 136 + fragoff] = f2bf(acc[nt][r] + bs);
  }
  asm volatile("s_waitcnt lgkmcnt(0)" ::: "memory");

  const int srow = lane >> 2, q = lane & 3;
  const int u = rb + srow;
  if (u < nrows) {
    short* orow = (isQ ? Q_sw + (size_t)u * 128 : PU + (size_t)u * 256) + q * 32;
    const short* sr = st + srow * 136 + q * 32;
#pragma unroll
    for (int i = 0; i < 4; ++i)
      *(bf16x8*)(orow + i * 8) = *(const bf16x8*)(sr + i * 8);
  }
}

// ---------------------------------------------------------------------------
// Fused scores+softmax+aggregation.  One wave per node, flash-style online
// softmax over tiles of 32 edges.  Per tile: gather P-half of PU rows ->
// h1 -> GEMM2 (w2 in LDS) -> w3 dot -> s into per-wave LDS slot buffer ->
// online max/denom update -> weighted accumulate from the e_u-half of the
// SAME PU rows (L1-hot).  s never touches HBM; b3 dropped (shift-invariant).
// ---------------------------------------------------------------------------
__global__ __launch_bounds__(256) void fused_sagg_kernel(
    const int* __restrict__ nodes, const int* __restrict__ neigh_idx,
    const int* __restrict__ off, const short* __restrict__ PU,
    const short* __restrict__ Q_sw, const short* __restrict__ w2bf,
    const float* __restrict__ b2, const float* __restrict__ w3v,
    const float* __restrict__ u2e, float* __restrict__ out) {
  __shared__ short w2l[16384];   // 32 KB
  __shared__ float sbuf[4][32];  // per-wave tile scores

  const int tid = threadIdx.x;
  const int lane = tid & 63, wv = tid >> 6;
  const int g = lane >> 4, lm = lane & 15;

#pragma unroll
  for (int i = 0; i < 8; ++i) {
    int o = (i * 256 + tid) << 3;
    *(bf16x8*)&w2l[o] = *(const bf16x8*)&w2bf[o];
  }
  __syncthreads();  // last block-wide barrier; per-wave code below

  const int node = blockIdx.x * 4 + wv;
  const int lo = off[node], hi = off[node + 1];
  float* orow = out + (size_t)node * EMBED;

  if (lo >= hi) {  // zero-degree fallback (exact fp32)
    const float* src = u2e + (size_t)nodes[node] * EMBED;
    orow[lane] = src[lane];
    orow[lane + 64] = src[lane + 64];
    return;
  }

  // Q fragments for this node (reused across all tiles)
  const short* qb = Q_sw + (size_t)node * 128;
  bf16x8 qf[4];
#pragma unroll
  for (int ks = 0; ks < 4; ++ks)
    qf[ks] = *(const bf16x8*)(qb + ((ks * 4 + g) << 3));

  float m_run = -3.402823466e38f, d_run = 0.f;
  f32x4 a0 = (f32x4){0.f, 0.f, 0.f, 0.f};
  f32x4 a1 = (f32x4){0.f, 0.f, 0.f, 0.f};

  for (int base = lo; base < hi; base += 32) {
    // ---- score phase: 32 slots (2 m-tiles of 16) ----
    bf16x8 h1[2][4];
#pragma unroll
    for (int mt = 0; mt < 2; ++mt) {
      int e = base + mt * 16 + lm;
      int ec = e < hi ? e : hi - 1;  // clamp: finite garbage, masked below
      const short* pb = PU + (size_t)neigh_idx[ec] * 256;
#pragma unroll
      for (int ks = 0; ks < 4; ++ks) {
        bf16x8 pa = *(const bf16x8*)(pb + ((ks * 4 + g) << 3));
        bf16x8 hh;
#pragma unroll
        for (int i = 0; i < 8; ++i)
          hh[i] = f2bf_trunc(fmaxf(bf2f(pa[i]) + bf2f(qf[ks][i]), 0.f));
        h1[mt][ks] = hh;
      }
    }

    f32x4 acc2[2][8];
#pragma unroll
    for (int mt = 0; mt < 2; ++mt)
#pragma unroll
      for (int nt = 0; nt < 8; ++nt) acc2[mt][nt] = (f32x4){0.f, 0.f, 0.f, 0.f};
#pragma unroll
    for (int ks = 0; ks < 4; ++ks) {
#pragma unroll
      for (int nt = 0; nt < 8; ++nt) {
        bf16x8 b = *(const bf16x8*)&w2l[((((ks * 4 + g) * 128) + nt * 16 + lm) << 3)];
        acc2[0][nt] = __builtin_amdgcn_mfma_f32_16x16x32_bf16(h1[0][ks], b, acc2[0][nt], 0, 0, 0);
        acc2[1][nt] = __builtin_amdgcn_mfma_f32_16x16x32_bf16(h1[1][ks], b, acc2[1][nt], 0, 0, 0);
      }
    }

    float part[2][4] = {{0.f, 0.f, 0.f, 0.f}, {0.f, 0.f, 0.f, 0.f}};
#pragma unroll
    for (int nt = 0; nt < 8; ++nt) {
      int n = nt * 16 + lm;
      float bias = b2[n];
      float w3n = w3v[n];
#pragma unroll
      for (int mt = 0; mt < 2; ++mt)
#pragma unroll
        for (int r = 0; r < 4; ++r)
          part[mt][r] += fmaxf(acc2[mt][nt][r] + bias, 0.f) * w3n;
    }
#pragma unroll
    for (int o2 = 1; o2 < 16; o2 <<= 1)
#pragma unroll
      for (int mt = 0; mt < 2; ++mt)
#pragma unroll
        for (int r = 0; r < 4; ++r)
          part[mt][r] += __shfl_xor(part[mt][r], o2, 64);
    if (lm == 0) {  // slot mt*16+4g+r
      *(f32x4*)&sbuf[wv][4 * g] =
          (f32x4){part[0][0], part[0][1], part[0][2], part[0][3]};
      *(f32x4*)&sbuf[wv][16 + 4 * g] =
          (f32x4){part[1][0], part[1][1], part[1][2], part[1][3]};
    }
    asm volatile("s_waitcnt lgkmcnt(0)" ::: "memory");  // wave-local drain

    // ---- online softmax bookkeeping ----
    int slot = lane & 31;
    float sv = sbuf[wv][slot];
    bool valid = (lane < 32) && (base + slot < hi);
    float mx = valid ? sv : -3.402823466e38f;
#pragma unroll
    for (int o2 = 1; o2 <= 32; o2 <<= 1) mx = fmaxf(mx, __shfl_xor(mx, o2, 64));
    float m_new = fmaxf(m_run, mx);
    float ex = valid ? __expf(sv - m_new) : 0.f;
#pragma unroll
    for (int o2 = 1; o2 <= 32; o2 <<= 1) ex += __shfl_xor(ex, o2, 64);
    float scale = __expf(m_run - m_new);  // 0 on first tile (underflow)
    d_run = d_run * scale + ex;
    a0 *= scale;
    a1 *= scale;
    m_run = m_new;

    // ---- aggregation: e_u-half of the same PU rows (L1-hot) ----
    for (int sl = g; sl < 32; sl += 4) {
      int e = base + sl;
      if (e >= hi) break;
      float w = __expf(sbuf[wv][sl] - m_new);
      bf16x8 r = *(const bf16x8*)(PU + (size_t)neigh_idx[e] * 256 + 128 + lm * 8);
#pragma unroll
      for (int c = 0; c < 4; ++c) {
        a0[c] += w * bf2f(r[c]);
        a1[c] += w * bf2f(r[c + 4]);
      }
    }
  }

  float inv = 1.0f / d_run;
  a0 *= inv;
  a1 *= inv;
#pragma unroll
  for (int o2 = 16; o2 <= 32; o2 <<= 1) {
#pragma unroll
    for (int c = 0; c < 4; ++c) {
      a0[c] += __shfl_xor(a0[c], o2, 64);
      a1[c] += __shfl_xor(a1[c], o2, 64);
    }
  }
  if (g == 0) {
    *(f32x4*)(orow + lm * 8) = a0;
    *(f32x4*)(orow + lm * 8 + 4) = a1;
  }
}

// ---------------------------------------------------------------------------
extern "C" void kernel_launch(void* const* d_in, const int* in_sizes, int n_in,
                              void* d_out, int out_size, void* d_ws, size_t ws_size,
                              hipStream_t stream) {
  const int* nodes  = (const int*)d_in[0];
  const int* neigh  = (const int*)d_in[1];
  const int* segs   = (const int*)d_in[2];
  const float* u2e  = (const float*)d_in[3];
  const float* w1   = (const float*)d_in[4];
  const float* b1   = (const float*)d_in[5];
  const float* w2   = (const float*)d_in[6];
  const float* b2   = (const float*)d_in[7];
  const float* w3   = (const float*)d_in[8];
  float* out = (float*)d_out;

  char* ws = (char*)d_ws;
  short* w1a  = (short*)(ws);                    // 32 KiB
  short* w1b  = (short*)(ws + 32768);            // 32 KiB
  short* w2bf = (short*)(ws + 65536);            // 32 KiB
  int*   off  = (int*)(ws + 98304);              // 40 KB (10001 ints)
  short* PU   = (short*)(ws + 139264);           // 51.2 MB (100000 x 512B)
  short* Q_sw = (short*)(ws + 139264 + 51200000);// 2.56 MB

  hipLaunchKernelGGL(prep_kernel, dim3(1250), dim3(256), 0, stream,
                     segs, w1, w2, off, w1a, w1b, w2bf);
  hipLaunchKernelGGL(row_gemm4_kernel, dim3(PBLK3 + QBLK3), dim3(256), 0, stream,
                     u2e, nodes, w1a, w1b, b1, PU, Q_sw);
  hipLaunchKernelGGL(fused_sagg_kernel, dim3(2500), dim3(256), 0, stream,
                     nodes, neigh, off, PU, Q_sw, w2bf, b2, w3, u2e, out);
}